// Round 2
// baseline (638.037 us; speedup 1.0000x reference)
//
#include <hip/hip_runtime.h>
#include <hip/hip_bf16.h>

typedef float ff4 __attribute__((ext_vector_type(4)));
typedef short s8v __attribute__((ext_vector_type(8)));
typedef unsigned int u2v __attribute__((ext_vector_type(2)));

#define Hd 1024
#define Nn 256
#define APAD 264   // bf16 stride for attn LDS tile (256 + 8 pad)

__device__ __forceinline__ unsigned bf16r(float f) {
    unsigned u = __builtin_bit_cast(unsigned, f);
    return (u + 0x7FFFu + ((u >> 16) & 1u)) >> 16;   // RNE f32->bf16
}

// ---- memBX rows 0..255 = bf16(mem) ----
__global__ void conv_mem_kernel(const float* __restrict__ mem, unsigned short* __restrict__ memBX) {
    int i = (blockIdx.x * 256 + threadIdx.x) * 4;
    ff4 v = *(const ff4*)(mem + i);
    u2v p;
    p[0] = bf16r(v[0]) | (bf16r(v[1]) << 16);
    p[1] = bf16r(v[2]) | (bf16r(v[3]) << 16);
    *(u2v*)(memBX + i) = p;
}

// ---- memBX rows 256,257 = bf16(W_out^T) ----
__global__ void conv_w_kernel(const float* __restrict__ Wout, unsigned short* __restrict__ memBX) {
    int t = blockIdx.x * 256 + threadIdx.x;   // 0..511
    int c = t >> 8;                           // 0 or 1
    int h0 = (t & 255) * 4;
    u2v p;
    p[0] = bf16r(Wout[h0 * 2 + c]) | (bf16r(Wout[(h0 + 1) * 2 + c]) << 16);
    p[1] = bf16r(Wout[(h0 + 2) * 2 + c]) | (bf16r(Wout[(h0 + 3) * 2 + c]) << 16);
    *(u2v*)(memBX + (size_t)(256 + c) * Hd + h0) = p;
}

// ---- Gram matrix G = mem @ mem^T  [256][256], bf16 ----
__global__ __launch_bounds__(256) void gram_kernel(const float* __restrict__ mem,
                                                   unsigned short* __restrict__ Gbf) {
    __shared__ float LA[32][132];
    __shared__ float LB[32][132];
    const int t = threadIdx.x;
    const int bi = blockIdx.x >> 3, bj = blockIdx.x & 7;
    const int j = t & 31, i0 = t >> 5;
    float acc0 = 0.f, acc1 = 0.f, acc2 = 0.f, acc3 = 0.f;
    for (int kc = 0; kc < Hd; kc += 128) {
        __syncthreads();
#pragma unroll
        for (int q = 0; q < 4; ++q) {
            int c = t + q * 256;
            int r = c >> 5, fc = (c & 31) << 2;
            *(ff4*)&LA[r][fc] = *(const ff4*)(mem + (size_t)(bi * 32 + r) * Hd + kc + fc);
            *(ff4*)&LB[r][fc] = *(const ff4*)(mem + (size_t)(bj * 32 + r) * Hd + kc + fc);
        }
        __syncthreads();
#pragma unroll 4
        for (int kk = 0; kk < 128; kk += 4) {
            ff4 b = *(const ff4*)&LB[j][kk];
            ff4 a0 = *(const ff4*)&LA[i0][kk];
            ff4 a1 = *(const ff4*)&LA[i0 + 8][kk];
            ff4 a2 = *(const ff4*)&LA[i0 + 16][kk];
            ff4 a3 = *(const ff4*)&LA[i0 + 24][kk];
            acc0 += a0[0]*b[0] + a0[1]*b[1] + a0[2]*b[2] + a0[3]*b[3];
            acc1 += a1[0]*b[0] + a1[1]*b[1] + a1[2]*b[2] + a1[3]*b[3];
            acc2 += a2[0]*b[0] + a2[1]*b[1] + a2[2]*b[2] + a2[3]*b[3];
            acc3 += a3[0]*b[0] + a3[1]*b[1] + a3[2]*b[2] + a3[3]*b[3];
        }
    }
    const int gj = bj * 32 + j;
    Gbf[(size_t)(bi * 32 + i0 +  0) * Nn + gj] = (unsigned short)bf16r(acc0);
    Gbf[(size_t)(bi * 32 + i0 +  8) * Nn + gj] = (unsigned short)bf16r(acc1);
    Gbf[(size_t)(bi * 32 + i0 + 16) * Nn + gj] = (unsigned short)bf16r(acc2);
    Gbf[(size_t)(bi * 32 + i0 + 24) * Nn + gj] = (unsigned short)bf16r(acc3);
}

// ---- fused main kernel: 4 independent waves x 16 rows, NO __syncthreads ----
__global__ __launch_bounds__(256, 3) void fused_kernel(
    const float* __restrict__ user, const float* __restrict__ music,
    const float* __restrict__ bout, const int* __restrict__ label,
    const unsigned short* __restrict__ memBX, const unsigned short* __restrict__ Gbf,
    float* __restrict__ out, float* __restrict__ partials)
{
    __shared__ __align__(16) unsigned short sAttn[4 * 16 * APAD];  // 33792 B

    const int t = threadIdx.x;
    const int w = t >> 6;
    const int l = t & 63;
    const int la = l & 15, lb = l >> 4;
    const int row0 = blockIdx.x * 64 + w * 16;     // this wave's first row

    const float* uR = user  + (size_t)(row0 + la) * Hd;
    const float* mR = music + (size_t)(row0 + la) * Hd;
    const unsigned short* Brow  = memBX + (size_t)la * Hd;             // + nt*16*Hd + col
    const unsigned short* BrowH = memBX + (size_t)(256 + (la < 2 ? la : 1)) * Hd;

    ff4 accL[16], accD[16];
#pragma unroll
    for (int i = 0; i < 16; ++i) { accL[i] = (ff4)0.0f; accD[i] = (ff4)0.0f; }
    ff4 accH = (ff4)0.0f;
    float sd2 = 0.f;

    // ---- main loop: per 32-col chunk, all operands straight from global ----
    for (int kc = 0; kc < Hd; kc += 32) {
        const int c0 = kc + (lb << 3);
        ff4 u0 = *(const ff4*)(uR + c0);
        ff4 u1 = *(const ff4*)(uR + c0 + 4);
        ff4 m0 = *(const ff4*)(mR + c0);
        ff4 m1 = *(const ff4*)(mR + c0 + 4);
        s8v aS, aD;
#pragma unroll
        for (int q = 0; q < 4; ++q) {
            float ss = u0[q] * m0[q], dd = u0[q] - m0[q];
            sd2 = fmaf(dd, dd, sd2);
            aS[q] = (short)bf16r(ss);
            aD[q] = (short)bf16r(dd);
        }
#pragma unroll
        for (int q = 0; q < 4; ++q) {
            float ss = u1[q] * m1[q], dd = u1[q] - m1[q];
            sd2 = fmaf(dd, dd, sd2);
            aS[4 + q] = (short)bf16r(ss);
            aD[4 + q] = (short)bf16r(dd);
        }
#pragma unroll
        for (int nt = 0; nt < 16; ++nt) {
            s8v bM = *(const s8v*)(Brow + (size_t)nt * 16 * Hd + c0);
            accL[nt] = __builtin_amdgcn_mfma_f32_16x16x32_bf16(aS, bM, accL[nt], 0, 0, 0);
            accD[nt] = __builtin_amdgcn_mfma_f32_16x16x32_bf16(aD, bM, accD[nt], 0, 0, 0);
        }
        s8v bW = *(const s8v*)(BrowH + c0);
        accH = __builtin_amdgcn_mfma_f32_16x16x32_bf16(aS, bW, accH, 0, 0, 0);
    }

    // ---- classification head (cols 0,1 live in lanes la=0,1) ----
    if (la < 2) {
#pragma unroll
        for (int j = 0; j < 4; ++j) {
            int gr = row0 + lb * 4 + j;
            out[1 + gr * 2 + la] = accH[j] + bout[la];
        }
    }
    // ---- ||d||^2 per row: reduce over the 4 lb col-blocks ----
    sd2 += __shfl_xor(sd2, 16);
    sd2 += __shfl_xor(sd2, 32);   // now every lane holds row (l&15)'s total

    // ---- softmax over n (C layout: col=la, row=lb*4+j) ----
    float mr0, mr1, mr2, mr3;
    {
        ff4 mx = accL[0];
#pragma unroll
        for (int nt = 1; nt < 16; ++nt) {
            mx[0] = fmaxf(mx[0], accL[nt][0]); mx[1] = fmaxf(mx[1], accL[nt][1]);
            mx[2] = fmaxf(mx[2], accL[nt][2]); mx[3] = fmaxf(mx[3], accL[nt][3]);
        }
#pragma unroll
        for (int s = 1; s < 16; s <<= 1) {
            mx[0] = fmaxf(mx[0], __shfl_xor(mx[0], s));
            mx[1] = fmaxf(mx[1], __shfl_xor(mx[1], s));
            mx[2] = fmaxf(mx[2], __shfl_xor(mx[2], s));
            mx[3] = fmaxf(mx[3], __shfl_xor(mx[3], s));
        }
        mr0 = mx[0]; mr1 = mx[1]; mr2 = mx[2]; mr3 = mx[3];
    }
    ff4 sumv = (ff4)0.0f;
#pragma unroll
    for (int nt = 0; nt < 16; ++nt) {
        accL[nt][0] = __expf(accL[nt][0] - mr0);
        accL[nt][1] = __expf(accL[nt][1] - mr1);
        accL[nt][2] = __expf(accL[nt][2] - mr2);
        accL[nt][3] = __expf(accL[nt][3] - mr3);
        sumv[0] += accL[nt][0]; sumv[1] += accL[nt][1];
        sumv[2] += accL[nt][2]; sumv[3] += accL[nt][3];
    }
#pragma unroll
    for (int s = 1; s < 16; s <<= 1) {
        sumv[0] += __shfl_xor(sumv[0], s); sumv[1] += __shfl_xor(sumv[1], s);
        sumv[2] += __shfl_xor(sumv[2], s); sumv[3] += __shfl_xor(sumv[3], s);
    }
    const float i0v = 1.0f / sumv[0], i1v = 1.0f / sumv[1];
    const float i2v = 1.0f / sumv[2], i3v = 1.0f / sumv[3];
    ff4 cross = (ff4)0.0f;
#pragma unroll
    for (int nt = 0; nt < 16; ++nt) {
        accL[nt][0] *= i0v; accL[nt][1] *= i1v; accL[nt][2] *= i2v; accL[nt][3] *= i3v;
        cross[0] = fmaf(accL[nt][0], accD[nt][0], cross[0]);
        cross[1] = fmaf(accL[nt][1], accD[nt][1], cross[1]);
        cross[2] = fmaf(accL[nt][2], accD[nt][2], cross[2]);
        cross[3] = fmaf(accL[nt][3], accD[nt][3], cross[3]);
    }
#pragma unroll
    for (int s = 1; s < 16; s <<= 1) {
        cross[0] += __shfl_xor(cross[0], s); cross[1] += __shfl_xor(cross[1], s);
        cross[2] += __shfl_xor(cross[2], s); cross[3] += __shfl_xor(cross[3], s);
    }

    // ---- stage attn (bf16) to this wave's LDS tile (wave-local transpose) ----
    unsigned short* myAttn = sAttn + w * (16 * APAD);
    {
        const int rb = lb << 2;
#pragma unroll
        for (int nt = 0; nt < 16; ++nt) {
            const int cc = nt * 16 + la;
            myAttn[(rb + 0) * APAD + cc] = (unsigned short)bf16r(accL[nt][0]);
            myAttn[(rb + 1) * APAD + cc] = (unsigned short)bf16r(accL[nt][1]);
            myAttn[(rb + 2) * APAD + cc] = (unsigned short)bf16r(accL[nt][2]);
            myAttn[(rb + 3) * APAD + cc] = (unsigned short)bf16r(accL[nt][3]);
        }
    }
    // same-wave LDS write->read: compiler inserts lgkmcnt wait; no block barrier needed

    // ---- gv = attn @ G (G symmetric -> row-major fragments valid as B) ----
    ff4 accG[16];
#pragma unroll
    for (int i = 0; i < 16; ++i) accG[i] = (ff4)0.0f;
#pragma unroll
    for (int ks = 0; ks < 8; ++ks) {
        const int ko = ks * 32 + (lb << 3);
        s8v aA = *(const s8v*)(myAttn + la * APAD + ko);
#pragma unroll
        for (int nt = 0; nt < 16; ++nt) {
            s8v bG = *(const s8v*)(Gbf + (size_t)(nt * 16 + la) * Nn + ko);
            accG[nt] = __builtin_amdgcn_mfma_f32_16x16x32_bf16(aA, bG, accG[nt], 0, 0, 0);
        }
    }
    ff4 quad = (ff4)0.0f;
#pragma unroll
    for (int nt = 0; nt < 16; ++nt) {
        quad[0] = fmaf(accL[nt][0], accG[nt][0], quad[0]);
        quad[1] = fmaf(accL[nt][1], accG[nt][1], quad[1]);
        quad[2] = fmaf(accL[nt][2], accG[nt][2], quad[2]);
        quad[3] = fmaf(accL[nt][3], accG[nt][3], quad[3]);
    }
#pragma unroll
    for (int s = 1; s < 16; s <<= 1) {
        quad[0] += __shfl_xor(quad[0], s); quad[1] += __shfl_xor(quad[1], s);
        quad[2] += __shfl_xor(quad[2], s); quad[3] += __shfl_xor(quad[3], s);
    }

    // ---- score & per-wave loss partial (no LDS, no barrier) ----
    float sdr = __shfl(sd2, lb * 4 + (la & 3));   // all lanes execute; sources 0..15 active
    float val = 0.f;
    if (la < 4) {
        const int r = lb * 4 + la;
        float cr = (la == 0) ? cross[0] : (la == 1) ? cross[1] : (la == 2) ? cross[2] : cross[3];
        float qd = (la == 0) ? quad[0]  : (la == 1) ? quad[1]  : (la == 2) ? quad[2]  : quad[3];
        float s2 = sdr + 2.0f * cr + qd;
        float sc = sqrtf(fmaxf(s2, 0.0f));
        const int gr = row0 + r;
        val = (float)(2 * label[gr] - 1) * sc;
    }
#pragma unroll
    for (int s = 1; s < 64; s <<= 1) val += __shfl_xor(val, s);
    if (l == 0) partials[blockIdx.x * 4 + w] = val;
}

// ---- deterministic final reduction of per-wave partials -> loss ----
__global__ void finalize_kernel(const float* __restrict__ partials, float* __restrict__ out,
                                int np, float invB) {
    const int t = threadIdx.x;
    float v = 0.f;
    for (int i = t; i < np; i += 256) v += partials[i];
#pragma unroll
    for (int s = 1; s < 64; s <<= 1) v += __shfl_xor(v, s);
    __shared__ float ws4[4];
    if ((t & 63) == 0) ws4[t >> 6] = v;
    __syncthreads();
    if (t == 0) out[0] = (ws4[0] + ws4[1] + ws4[2] + ws4[3]) * invB;
}

extern "C" void kernel_launch(void* const* d_in, const int* in_sizes, int n_in,
                              void* d_out, int out_size, void* d_ws, size_t ws_size,
                              hipStream_t stream) {
    const float* user  = (const float*)d_in[0];
    const float* music = (const float*)d_in[1];
    const float* mem   = (const float*)d_in[2];
    const float* Wout  = (const float*)d_in[3];
    const float* bout  = (const float*)d_in[4];
    const int*   label = (const int*)d_in[5];
    const int Bn   = in_sizes[0] / Hd;   // 65536
    const int nblk = Bn / 64;            // 1024

    unsigned short* memBX = (unsigned short*)d_ws;                       // [258][1024] bf16
    unsigned short* Gbf   = (unsigned short*)((char*)d_ws + (size_t)258 * Hd * 2);
    float* partials       = (float*)((char*)d_ws + (size_t)258 * Hd * 2 + (size_t)Nn * Nn * 2);

    conv_mem_kernel<<<(Nn * Hd) / 1024, 256, 0, stream>>>(mem, memBX);
    conv_w_kernel<<<2, 256, 0, stream>>>(Wout, memBX);
    gram_kernel<<<64, 256, 0, stream>>>(mem, Gbf);
    fused_kernel<<<nblk, 256, 0, stream>>>(user, music, bout, label, memBX, Gbf,
                                           (float*)d_out, partials);
    finalize_kernel<<<1, 256, 0, stream>>>(partials, (float*)d_out, nblk * 4, 1.0f / (float)Bn);
}

// Round 3
// 255.622 us; speedup vs baseline: 2.4960x; 2.4960x over previous
//
#include <hip/hip_runtime.h>
#include <hip/hip_bf16.h>

typedef float ff4 __attribute__((ext_vector_type(4)));
typedef short s8v __attribute__((ext_vector_type(8)));
typedef unsigned int u4v __attribute__((ext_vector_type(4)));

#define Hd 1024
#define Nn 256
#define KC 32
#define NCHUNK 32
#define SPAD 36    // ushorts per row in sS/sD (32 + 4 pad)
#define APAD 264   // bf16 stride for attn LDS tile

__device__ __forceinline__ unsigned bf16r(float f) {
    unsigned u = __builtin_bit_cast(unsigned, f);
    return (u + 0x7FFFu + ((u >> 16) & 1u)) >> 16;   // RNE f32->bf16
}

__device__ __forceinline__ void glds16(void* lds, const void* g) {
    __builtin_amdgcn_global_load_lds(
        (const __attribute__((address_space(1))) unsigned int*)g,
        (__attribute__((address_space(3))) unsigned int*)lds, 16, 0, 0);
}

// ---- memB chunk-major: byte (c*16384 + row*64 + col*2) = bf16(mem[row][c*32+col]) ----
__global__ void conv_mem_kernel(const float* __restrict__ mem, unsigned short* __restrict__ memB) {
    int g = blockIdx.x * 256 + threadIdx.x;          // 0..32767, one 16B block each
    int c = g >> 10;                                 // chunk 0..31
    int r = (g >> 2) & 255;                          // row 0..255
    int col0 = (g & 3) * 8;                          // 0,8,16,24
    const float* src = mem + (size_t)r * Hd + c * KC + col0;
    ff4 a = *(const ff4*)src;
    ff4 b = *(const ff4*)(src + 4);
    u4v v;
    v[0] = bf16r(a[0]) | (bf16r(a[1]) << 16);
    v[1] = bf16r(a[2]) | (bf16r(a[3]) << 16);
    v[2] = bf16r(b[0]) | (bf16r(b[1]) << 16);
    v[3] = bf16r(b[2]) | (bf16r(b[3]) << 16);
    *(u4v*)(memB + (size_t)g * 8) = v;
}

// ---- Wbf[c][h] = bf16(Wout[h][c]), c in {0,1} ----
__global__ void conv_w_kernel(const float* __restrict__ Wout, unsigned short* __restrict__ Wbf) {
    int t = threadIdx.x;            // 256 threads
    int c = t >> 7;                 // 0 or 1
    int h0 = (t & 127) * 8;
    u4v v;
#pragma unroll
    for (int j = 0; j < 4; ++j) {
        unsigned lo = bf16r(Wout[(h0 + 2 * j) * 2 + c]);
        unsigned hi = bf16r(Wout[(h0 + 2 * j + 1) * 2 + c]);
        v[j] = lo | (hi << 16);
    }
    *(u4v*)(Wbf + (size_t)c * Hd + h0) = v;
}

// ---- Gram matrix G = mem @ mem^T  [256][256], bf16 ----
__global__ __launch_bounds__(256) void gram_kernel(const float* __restrict__ mem,
                                                   unsigned short* __restrict__ Gbf) {
    __shared__ float LA[32][132];
    __shared__ float LB[32][132];
    const int t = threadIdx.x;
    const int bi = blockIdx.x >> 3, bj = blockIdx.x & 7;
    const int j = t & 31, i0 = t >> 5;
    float acc0 = 0.f, acc1 = 0.f, acc2 = 0.f, acc3 = 0.f;
    for (int kc = 0; kc < Hd; kc += 128) {
        __syncthreads();
#pragma unroll
        for (int q = 0; q < 4; ++q) {
            int c = t + q * 256;
            int r = c >> 5, fc = (c & 31) << 2;
            *(ff4*)&LA[r][fc] = *(const ff4*)(mem + (size_t)(bi * 32 + r) * Hd + kc + fc);
            *(ff4*)&LB[r][fc] = *(const ff4*)(mem + (size_t)(bj * 32 + r) * Hd + kc + fc);
        }
        __syncthreads();
#pragma unroll 4
        for (int kk = 0; kk < 128; kk += 4) {
            ff4 b = *(const ff4*)&LB[j][kk];
            ff4 a0 = *(const ff4*)&LA[i0][kk];
            ff4 a1 = *(const ff4*)&LA[i0 + 8][kk];
            ff4 a2 = *(const ff4*)&LA[i0 + 16][kk];
            ff4 a3 = *(const ff4*)&LA[i0 + 24][kk];
            acc0 += a0[0]*b[0] + a0[1]*b[1] + a0[2]*b[2] + a0[3]*b[3];
            acc1 += a1[0]*b[0] + a1[1]*b[1] + a1[2]*b[2] + a1[3]*b[3];
            acc2 += a2[0]*b[0] + a2[1]*b[1] + a2[2]*b[2] + a2[3]*b[3];
            acc3 += a3[0]*b[0] + a3[1]*b[1] + a3[2]*b[2] + a3[3]*b[3];
        }
    }
    const int gj = bj * 32 + j;
    Gbf[(size_t)(bi * 32 + i0 +  0) * Nn + gj] = (unsigned short)bf16r(acc0);
    Gbf[(size_t)(bi * 32 + i0 +  8) * Nn + gj] = (unsigned short)bf16r(acc1);
    Gbf[(size_t)(bi * 32 + i0 + 16) * Nn + gj] = (unsigned short)bf16r(acc2);
    Gbf[(size_t)(bi * 32 + i0 + 24) * Nn + gj] = (unsigned short)bf16r(acc3);
}

// ---- fused main kernel: 64 rows/block, 4 waves, 1 barrier/chunk, dbuf LDS ----
__global__ __launch_bounds__(256, 2) void fused_kernel(
    const float* __restrict__ user, const float* __restrict__ music,
    const float* __restrict__ bout, const int* __restrict__ label,
    const unsigned short* __restrict__ memB,   // chunk-major [32][256][32] bf16
    const unsigned short* __restrict__ Wbf,    // [2][1024] bf16
    const unsigned short* __restrict__ Gbf,    // [256][256] bf16
    float* __restrict__ out, float* __restrict__ partials)
{
    __shared__ __align__(16) unsigned char smem[51200];
    unsigned short* sM = (unsigned short*)smem;                 // 2 x 16384 B
    unsigned short* sS = (unsigned short*)(smem + 32768);       // 2 x 4608 B
    unsigned short* sD = (unsigned short*)(smem + 41984);       // 2 x 4608 B
    unsigned short* sAttn = (unsigned short*)smem;              // alias (epilogue)

    const int t = threadIdx.x;
    const int w = t >> 6;
    const int l = t & 63;
    const int la = l & 15, lb = l >> 4;
    const int row0 = blockIdx.x * 64;
    const int sr = t >> 2, kp = t & 3;

    const float* uR = user  + (size_t)(row0 + sr) * Hd + kp * 8;
    const float* mR = music + (size_t)(row0 + sr) * Hd + kp * 8;
    const char* gsrc = (const char*)memB + w * 4096 + l * 16;   // + c*16384 + i*1024

    ff4 accL[16], accD[16];
#pragma unroll
    for (int i = 0; i < 16; ++i) { accL[i] = (ff4)0.0f; accD[i] = (ff4)0.0f; }
    ff4 accH = (ff4)0.0f;
    float sd2 = 0.f;

    // ---- prologue: stage chunk 0 ----
#pragma unroll
    for (int i = 0; i < 4; ++i)
        glds16(smem + w * 4096 + i * 1024, gsrc + i * 1024);
    {
        ff4 ua = *(const ff4*)(uR), ub = *(const ff4*)(uR + 4);
        ff4 ma = *(const ff4*)(mR), mb = *(const ff4*)(mR + 4);
        u4v vs, vd;
#pragma unroll
        for (int j = 0; j < 2; ++j) {
            ff4 uu = j ? ub : ua, mm = j ? mb : ma;
            float s0 = uu[0]*mm[0], s1 = uu[1]*mm[1], s2 = uu[2]*mm[2], s3 = uu[3]*mm[3];
            float d0 = uu[0]-mm[0], d1 = uu[1]-mm[1], d2 = uu[2]-mm[2], d3 = uu[3]-mm[3];
            sd2 = fmaf(d0,d0,sd2); sd2 = fmaf(d1,d1,sd2); sd2 = fmaf(d2,d2,sd2); sd2 = fmaf(d3,d3,sd2);
            vs[2*j]   = bf16r(s0) | (bf16r(s1) << 16);
            vs[2*j+1] = bf16r(s2) | (bf16r(s3) << 16);
            vd[2*j]   = bf16r(d0) | (bf16r(d1) << 16);
            vd[2*j+1] = bf16r(d2) | (bf16r(d3) << 16);
        }
        *(u4v*)(sS + sr * SPAD + kp * 8) = vs;
        *(u4v*)(sD + sr * SPAD + kp * 8) = vd;
    }
    __syncthreads();   // drains vmcnt: sM buf0 + sS/sD buf0 ready

    // ---- main loop: 1 barrier per chunk ----
    for (int c = 0; c < NCHUNK; ++c) {
        const int cur = c & 1;
        // bW first (so later prefetch keeps its vmcnt count high)
        s8v bW = *(const s8v*)(Wbf + (size_t)(la < 2 ? la : 1) * Hd + c * KC + lb * 8);
        ff4 pua, pub, pma, pmb;
        if (c + 1 < NCHUNK) {
            // prefetch chunk c+1: mem tile direct-to-LDS, u/m to regs
#pragma unroll
            for (int i = 0; i < 4; ++i)
                glds16(smem + (cur ^ 1) * 16384 + w * 4096 + i * 1024,
                       gsrc + (size_t)(c + 1) * 16384 + i * 1024);
            pua = *(const ff4*)(uR + (c + 1) * KC);
            pub = *(const ff4*)(uR + (c + 1) * KC + 4);
            pma = *(const ff4*)(mR + (c + 1) * KC);
            pmb = *(const ff4*)(mR + (c + 1) * KC + 4);
        }
        // MFMA phase over chunk c
        s8v aS = *(const s8v*)(sS + cur * 2304 + (w * 16 + la) * SPAD + lb * 8);
        s8v aD = *(const s8v*)(sD + cur * 2304 + (w * 16 + la) * SPAD + lb * 8);
#pragma unroll
        for (int nt = 0; nt < 16; ++nt) {
            s8v bM = *(const s8v*)(sM + cur * 8192 + (nt * 16 + la) * 32 + lb * 8);
            accL[nt] = __builtin_amdgcn_mfma_f32_16x16x32_bf16(aS, bM, accL[nt], 0, 0, 0);
            accD[nt] = __builtin_amdgcn_mfma_f32_16x16x32_bf16(aD, bM, accD[nt], 0, 0, 0);
        }
        accH = __builtin_amdgcn_mfma_f32_16x16x32_bf16(aS, bW, accH, 0, 0, 0);
        // pack chunk c+1 into the other buffer
        if (c + 1 < NCHUNK) {
            u4v vs, vd;
#pragma unroll
            for (int j = 0; j < 2; ++j) {
                ff4 uu = j ? pub : pua, mm = j ? pmb : pma;
                float s0 = uu[0]*mm[0], s1 = uu[1]*mm[1], s2 = uu[2]*mm[2], s3 = uu[3]*mm[3];
                float d0 = uu[0]-mm[0], d1 = uu[1]-mm[1], d2 = uu[2]-mm[2], d3 = uu[3]-mm[3];
                sd2 = fmaf(d0,d0,sd2); sd2 = fmaf(d1,d1,sd2); sd2 = fmaf(d2,d2,sd2); sd2 = fmaf(d3,d3,sd2);
                vs[2*j]   = bf16r(s0) | (bf16r(s1) << 16);
                vs[2*j+1] = bf16r(s2) | (bf16r(s3) << 16);
                vd[2*j]   = bf16r(d0) | (bf16r(d1) << 16);
                vd[2*j+1] = bf16r(d2) | (bf16r(d3) << 16);
            }
            *(u4v*)(sS + (cur ^ 1) * 2304 + sr * SPAD + kp * 8) = vs;
            *(u4v*)(sD + (cur ^ 1) * 2304 + sr * SPAD + kp * 8) = vd;
        }
        __syncthreads();   // full drain: glds(c+1) + ds_writes visible; sM/sS/sD bufs flip
    }

    // ---- classification head (cols 0,1 live in lanes la=0,1) ----
    if (la < 2) {
#pragma unroll
        for (int j = 0; j < 4; ++j) {
            int gr = row0 + w * 16 + lb * 4 + j;
            out[1 + gr * 2 + la] = accH[j] + bout[la];
        }
    }
    // ---- ||d||^2 per row: reduce over the 4 kp col-parts ----
    sd2 += __shfl_xor(sd2, 1);
    sd2 += __shfl_xor(sd2, 2);   // lane 4*(row&15)+kp holds row (w*16 + (l>>2))'s total

    // ---- softmax over n (C layout: col=la, row=lb*4+j) ----
    float mr0, mr1, mr2, mr3;
    {
        ff4 mx = accL[0];
#pragma unroll
        for (int nt = 1; nt < 16; ++nt) {
            mx[0] = fmaxf(mx[0], accL[nt][0]); mx[1] = fmaxf(mx[1], accL[nt][1]);
            mx[2] = fmaxf(mx[2], accL[nt][2]); mx[3] = fmaxf(mx[3], accL[nt][3]);
        }
#pragma unroll
        for (int s = 1; s < 16; s <<= 1) {
            mx[0] = fmaxf(mx[0], __shfl_xor(mx[0], s));
            mx[1] = fmaxf(mx[1], __shfl_xor(mx[1], s));
            mx[2] = fmaxf(mx[2], __shfl_xor(mx[2], s));
            mx[3] = fmaxf(mx[3], __shfl_xor(mx[3], s));
        }
        mr0 = mx[0]; mr1 = mx[1]; mr2 = mx[2]; mr3 = mx[3];
    }
    ff4 sumv = (ff4)0.0f;
#pragma unroll
    for (int nt = 0; nt < 16; ++nt) {
        accL[nt][0] = __expf(accL[nt][0] - mr0);
        accL[nt][1] = __expf(accL[nt][1] - mr1);
        accL[nt][2] = __expf(accL[nt][2] - mr2);
        accL[nt][3] = __expf(accL[nt][3] - mr3);
        sumv[0] += accL[nt][0]; sumv[1] += accL[nt][1];
        sumv[2] += accL[nt][2]; sumv[3] += accL[nt][3];
    }
#pragma unroll
    for (int s = 1; s < 16; s <<= 1) {
        sumv[0] += __shfl_xor(sumv[0], s); sumv[1] += __shfl_xor(sumv[1], s);
        sumv[2] += __shfl_xor(sumv[2], s); sumv[3] += __shfl_xor(sumv[3], s);
    }
    const float i0v = 1.0f / sumv[0], i1v = 1.0f / sumv[1];
    const float i2v = 1.0f / sumv[2], i3v = 1.0f / sumv[3];
    ff4 cross = (ff4)0.0f;
#pragma unroll
    for (int nt = 0; nt < 16; ++nt) {
        accL[nt][0] *= i0v; accL[nt][1] *= i1v; accL[nt][2] *= i2v; accL[nt][3] *= i3v;
        cross[0] = fmaf(accL[nt][0], accD[nt][0], cross[0]);
        cross[1] = fmaf(accL[nt][1], accD[nt][1], cross[1]);
        cross[2] = fmaf(accL[nt][2], accD[nt][2], cross[2]);
        cross[3] = fmaf(accL[nt][3], accD[nt][3], cross[3]);
    }
#pragma unroll
    for (int s = 1; s < 16; s <<= 1) {
        cross[0] += __shfl_xor(cross[0], s); cross[1] += __shfl_xor(cross[1], s);
        cross[2] += __shfl_xor(cross[2], s); cross[3] += __shfl_xor(cross[3], s);
    }

    // ---- stage attn (bf16) to this wave's LDS tile (aliases sM/sS region) ----
    unsigned short* myAttn = sAttn + w * (16 * APAD);
    {
        const int rb = lb << 2;
#pragma unroll
        for (int nt = 0; nt < 16; ++nt) {
            const int cc = nt * 16 + la;
            myAttn[(rb + 0) * APAD + cc] = (unsigned short)bf16r(accL[nt][0]);
            myAttn[(rb + 1) * APAD + cc] = (unsigned short)bf16r(accL[nt][1]);
            myAttn[(rb + 2) * APAD + cc] = (unsigned short)bf16r(accL[nt][2]);
            myAttn[(rb + 3) * APAD + cc] = (unsigned short)bf16r(accL[nt][3]);
        }
    }
    // same-wave write->read: lgkmcnt ordering handled by compiler

    // ---- gv = attn @ G (G symmetric -> row-major fragments valid as B) ----
    ff4 accG[16];
#pragma unroll
    for (int i = 0; i < 16; ++i) accG[i] = (ff4)0.0f;
#pragma unroll
    for (int ks = 0; ks < 8; ++ks) {
        const int ko = ks * 32 + (lb << 3);
        s8v aA = *(const s8v*)(myAttn + la * APAD + ko);
#pragma unroll
        for (int nt = 0; nt < 16; ++nt) {
            s8v bG = *(const s8v*)(Gbf + (size_t)(nt * 16 + la) * Nn + ko);
            accG[nt] = __builtin_amdgcn_mfma_f32_16x16x32_bf16(aA, bG, accG[nt], 0, 0, 0);
        }
    }
    ff4 quad = (ff4)0.0f;
#pragma unroll
    for (int nt = 0; nt < 16; ++nt) {
        quad[0] = fmaf(accL[nt][0], accG[nt][0], quad[0]);
        quad[1] = fmaf(accL[nt][1], accG[nt][1], quad[1]);
        quad[2] = fmaf(accL[nt][2], accG[nt][2], quad[2]);
        quad[3] = fmaf(accL[nt][3], accG[nt][3], quad[3]);
    }
#pragma unroll
    for (int s = 1; s < 16; s <<= 1) {
        quad[0] += __shfl_xor(quad[0], s); quad[1] += __shfl_xor(quad[1], s);
        quad[2] += __shfl_xor(quad[2], s); quad[3] += __shfl_xor(quad[3], s);
    }

    // ---- score & per-wave loss partial ----
    float sdr = __shfl(sd2, (((lb << 2) + la) << 2) & 63);  // row (lb*4+la)'s ||d||^2
    float val = 0.f;
    if (la < 4) {
        const int r = lb * 4 + la;
        float cr = (la == 0) ? cross[0] : (la == 1) ? cross[1] : (la == 2) ? cross[2] : cross[3];
        float qd = (la == 0) ? quad[0]  : (la == 1) ? quad[1]  : (la == 2) ? quad[2]  : quad[3];
        float s2 = sdr + 2.0f * cr + qd;
        float sc = sqrtf(fmaxf(s2, 0.0f));
        const int gr = row0 + w * 16 + r;
        val = (float)(2 * label[gr] - 1) * sc;
    }
#pragma unroll
    for (int s = 1; s < 64; s <<= 1) val += __shfl_xor(val, s);
    if (l == 0) partials[blockIdx.x * 4 + w] = val;
}

// ---- deterministic final reduction of per-wave partials -> loss ----
__global__ void finalize_kernel(const float* __restrict__ partials, float* __restrict__ out,
                                int np, float invB) {
    const int t = threadIdx.x;
    float v = 0.f;
    for (int i = t; i < np; i += 256) v += partials[i];
#pragma unroll
    for (int s = 1; s < 64; s <<= 1) v += __shfl_xor(v, s);
    __shared__ float ws4[4];
    if ((t & 63) == 0) ws4[t >> 6] = v;
    __syncthreads();
    if (t == 0) out[0] = (ws4[0] + ws4[1] + ws4[2] + ws4[3]) * invB;
}

extern "C" void kernel_launch(void* const* d_in, const int* in_sizes, int n_in,
                              void* d_out, int out_size, void* d_ws, size_t ws_size,
                              hipStream_t stream) {
    const float* user  = (const float*)d_in[0];
    const float* music = (const float*)d_in[1];
    const float* mem   = (const float*)d_in[2];
    const float* Wout  = (const float*)d_in[3];
    const float* bout  = (const float*)d_in[4];
    const int*   label = (const int*)d_in[5];
    const int Bn   = in_sizes[0] / Hd;   // 65536
    const int nblk = Bn / 64;            // 1024

    unsigned short* memB = (unsigned short*)d_ws;                                  // 512 KB
    unsigned short* Wbf  = (unsigned short*)((char*)d_ws + 524288);                // 4 KB
    unsigned short* Gbf  = (unsigned short*)((char*)d_ws + 524288 + 4096);         // 128 KB
    float* partials      = (float*)((char*)d_ws + 524288 + 4096 + 131072);         // 16 KB

    conv_mem_kernel<<<128, 256, 0, stream>>>(mem, memB);
    conv_w_kernel<<<1, 256, 0, stream>>>(Wout, Wbf);
    gram_kernel<<<64, 256, 0, stream>>>(mem, Gbf);
    fused_kernel<<<nblk, 256, 0, stream>>>(user, music, bout, label, memB, Wbf, Gbf,
                                           (float*)d_out, partials);
    finalize_kernel<<<1, 256, 0, stream>>>(partials, (float*)d_out, nblk * 4, 1.0f / (float)Bn);
}

// Round 4
// 217.240 us; speedup vs baseline: 2.9370x; 1.1767x over previous
//
#include <hip/hip_runtime.h>
#include <hip/hip_bf16.h>

typedef float ff4 __attribute__((ext_vector_type(4)));
typedef short s8v __attribute__((ext_vector_type(8)));
typedef unsigned int u4v __attribute__((ext_vector_type(4)));
typedef unsigned int u2v __attribute__((ext_vector_type(2)));

#define Hd 1024
#define Nn 256
#define KC 64
#define NCHUNK 16
#define APAD 264   // bf16 stride for attn LDS tile

__device__ __forceinline__ unsigned bf16r(float f) {
    unsigned u = __builtin_bit_cast(unsigned, f);
    return (u + 0x7FFFu + ((u >> 16) & 1u)) >> 16;   // RNE f32->bf16
}

__device__ __forceinline__ void glds16(void* lds, const void* g) {
    __builtin_amdgcn_global_load_lds(
        (const __attribute__((address_space(1))) unsigned int*)g,
        (__attribute__((address_space(3))) unsigned int*)lds, 16, 0, 0);
}

// ---- memB chunk-major + block-swizzled:
// byte(c, r, b) at c*32768 + r*128 + (b ^ (r&7))*16 holds bf16(mem[r][c*64 + b*8 .. +8])
__global__ void conv_mem_kernel(const float* __restrict__ mem, unsigned short* __restrict__ memB) {
    int g = blockIdx.x * 256 + threadIdx.x;   // 0..32767
    int b = g & 7;
    int r = (g >> 3) & 255;
    int c = g >> 11;
    const float* src = mem + (size_t)r * Hd + c * KC + b * 8;
    ff4 a0 = *(const ff4*)src;
    ff4 a1 = *(const ff4*)(src + 4);
    u4v v;
    v[0] = bf16r(a0[0]) | (bf16r(a0[1]) << 16);
    v[1] = bf16r(a0[2]) | (bf16r(a0[3]) << 16);
    v[2] = bf16r(a1[0]) | (bf16r(a1[1]) << 16);
    v[3] = bf16r(a1[2]) | (bf16r(a1[3]) << 16);
    size_t dst = (size_t)c * 32768 + (size_t)r * 128 + (size_t)((b ^ (r & 7)) * 16);
    *(u4v*)((char*)memB + dst) = v;
}

// ---- Wbf[c][h] = bf16(Wout[h][c]), c in {0,1} ----
__global__ void conv_w_kernel(const float* __restrict__ Wout, unsigned short* __restrict__ Wbf) {
    int t = threadIdx.x;
    int c = t >> 7;
    int h0 = (t & 127) * 8;
    u4v v;
#pragma unroll
    for (int j = 0; j < 4; ++j) {
        unsigned lo = bf16r(Wout[(h0 + 2 * j) * 2 + c]);
        unsigned hi = bf16r(Wout[(h0 + 2 * j + 1) * 2 + c]);
        v[j] = lo | (hi << 16);
    }
    *(u4v*)(Wbf + (size_t)c * Hd + h0) = v;
}

// ---- Gram matrix G = mem @ mem^T  [256][256], bf16 ----
__global__ __launch_bounds__(256) void gram_kernel(const float* __restrict__ mem,
                                                   unsigned short* __restrict__ Gbf) {
    __shared__ float LA[32][132];
    __shared__ float LB[32][132];
    const int t = threadIdx.x;
    const int bi = blockIdx.x >> 3, bj = blockIdx.x & 7;
    const int j = t & 31, i0 = t >> 5;
    float acc0 = 0.f, acc1 = 0.f, acc2 = 0.f, acc3 = 0.f;
    for (int kc = 0; kc < Hd; kc += 128) {
        __syncthreads();
#pragma unroll
        for (int q = 0; q < 4; ++q) {
            int c = t + q * 256;
            int r = c >> 5, fc = (c & 31) << 2;
            *(ff4*)&LA[r][fc] = *(const ff4*)(mem + (size_t)(bi * 32 + r) * Hd + kc + fc);
            *(ff4*)&LB[r][fc] = *(const ff4*)(mem + (size_t)(bj * 32 + r) * Hd + kc + fc);
        }
        __syncthreads();
#pragma unroll 4
        for (int kk = 0; kk < 128; kk += 4) {
            ff4 b = *(const ff4*)&LB[j][kk];
            ff4 a0 = *(const ff4*)&LA[i0][kk];
            ff4 a1 = *(const ff4*)&LA[i0 + 8][kk];
            ff4 a2 = *(const ff4*)&LA[i0 + 16][kk];
            ff4 a3 = *(const ff4*)&LA[i0 + 24][kk];
            acc0 += a0[0]*b[0] + a0[1]*b[1] + a0[2]*b[2] + a0[3]*b[3];
            acc1 += a1[0]*b[0] + a1[1]*b[1] + a1[2]*b[2] + a1[3]*b[3];
            acc2 += a2[0]*b[0] + a2[1]*b[1] + a2[2]*b[2] + a2[3]*b[3];
            acc3 += a3[0]*b[0] + a3[1]*b[1] + a3[2]*b[2] + a3[3]*b[3];
        }
    }
    const int gj = bj * 32 + j;
    Gbf[(size_t)(bi * 32 + i0 +  0) * Nn + gj] = (unsigned short)bf16r(acc0);
    Gbf[(size_t)(bi * 32 + i0 +  8) * Nn + gj] = (unsigned short)bf16r(acc1);
    Gbf[(size_t)(bi * 32 + i0 + 16) * Nn + gj] = (unsigned short)bf16r(acc2);
    Gbf[(size_t)(bi * 32 + i0 + 24) * Nn + gj] = (unsigned short)bf16r(acc3);
}

struct Frags { s8v s0, s1, d0, d1; };
struct UMr { ff4 ua, ub, uc, ud, ma, mb, mc, md; };

__device__ __forceinline__ void load_um(UMr& r, const float* uR, const float* mR, int c) {
    const float* up = uR + c * KC;
    const float* mp = mR + c * KC;
    r.ua = *(const ff4*)(up);      r.ub = *(const ff4*)(up + 4);
    r.uc = *(const ff4*)(up + 32); r.ud = *(const ff4*)(up + 36);
    r.ma = *(const ff4*)(mp);      r.mb = *(const ff4*)(mp + 4);
    r.mc = *(const ff4*)(mp + 32); r.md = *(const ff4*)(mp + 36);
}

__device__ __forceinline__ void cvt_frag(const UMr& r, Frags& f, float& sd2) {
    s8v as, ad;
#pragma unroll
    for (int q = 0; q < 4; ++q) {
        float ss = r.ua[q]*r.ma[q], dd = r.ua[q]-r.ma[q];
        sd2 = fmaf(dd, dd, sd2);
        as[q] = (short)bf16r(ss); ad[q] = (short)bf16r(dd);
    }
#pragma unroll
    for (int q = 0; q < 4; ++q) {
        float ss = r.ub[q]*r.mb[q], dd = r.ub[q]-r.mb[q];
        sd2 = fmaf(dd, dd, sd2);
        as[4+q] = (short)bf16r(ss); ad[4+q] = (short)bf16r(dd);
    }
    f.s0 = as; f.d0 = ad;
#pragma unroll
    for (int q = 0; q < 4; ++q) {
        float ss = r.uc[q]*r.mc[q], dd = r.uc[q]-r.mc[q];
        sd2 = fmaf(dd, dd, sd2);
        as[q] = (short)bf16r(ss); ad[q] = (short)bf16r(dd);
    }
#pragma unroll
    for (int q = 0; q < 4; ++q) {
        float ss = r.ud[q]*r.md[q], dd = r.ud[q]-r.md[q];
        sd2 = fmaf(dd, dd, sd2);
        as[4+q] = (short)bf16r(ss); ad[4+q] = (short)bf16r(dd);
    }
    f.s1 = as; f.d1 = ad;
}

// ---- fused main kernel: 64 rows/block (4 waves x 16 rows), raw-barrier pipeline ----
__global__ __launch_bounds__(256, 2) void fused_kernel(
    const float* __restrict__ user, const float* __restrict__ music,
    const float* __restrict__ bout, const int* __restrict__ label,
    const unsigned short* __restrict__ memB,   // [16][256][64] bf16, block-swizzled
    const unsigned short* __restrict__ Wbf,    // [2][1024] bf16
    const unsigned short* __restrict__ Gbf,    // [256][256] bf16
    float* __restrict__ out, float* __restrict__ partials)
{
    __shared__ __align__(16) unsigned char smem[65536];          // 2 x 32768 sM dbuf
    unsigned short* sAttn = (unsigned short*)smem;               // alias (epilogue)

    const int t = threadIdx.x;
    const int w = t >> 6;
    const int l = t & 63;
    const int la = l & 15, lb = l >> 4;
    const int row0 = blockIdx.x * 64;
    const int myrow = row0 + w * 16 + la;

    const float* uR = user  + (size_t)myrow * Hd + lb * 8;
    const float* mR = music + (size_t)myrow * Hd + lb * 8;
    const char* gsrcW = (const char*)memB + w * 8192 + l * 16;
    const unsigned short* wrowB = Wbf + (size_t)(la < 2 ? la : 1) * Hd + lb * 8;

    const int off0 = la * 128 + ((lb) ^ (la & 7)) * 16;
    const int off1 = la * 128 + ((4 + lb) ^ (la & 7)) * 16;

    ff4 accL[16], accD[16];
#pragma unroll
    for (int i = 0; i < 16; ++i) { accL[i] = (ff4)0.0f; accD[i] = (ff4)0.0f; }
    ff4 accH = (ff4)0.0f;
    float sd2 = 0.f;

    Frags fA, fB;
    UMr um;

    // ---- prologue: stage chunk 0 ----
#pragma unroll
    for (int i = 0; i < 8; ++i)
        glds16(smem + w * 8192 + i * 1024, gsrcW + i * 1024);
    __builtin_amdgcn_sched_barrier(0);
    load_um(um, uR, mR, 0);
    cvt_frag(um, fA, sd2);
    __builtin_amdgcn_sched_barrier(0);
    asm volatile("s_waitcnt vmcnt(0)" ::: "memory");
    __builtin_amdgcn_s_barrier();
    __builtin_amdgcn_sched_barrier(0);

#define CHUNK_BODY(C, FC, FN, PF)                                               \
    {                                                                           \
        const int bsel = (C) & 1;                                               \
        if (PF) {                                                               \
            const char* gs = gsrcW + (size_t)((C) + 1) * 32768;                 \
            _Pragma("unroll")                                                   \
            for (int i = 0; i < 8; ++i)                                         \
                glds16(smem + (bsel ^ 1) * 32768 + w * 8192 + i * 1024,         \
                       gs + i * 1024);                                          \
            __builtin_amdgcn_sched_barrier(0);                                  \
        }                                                                       \
        s8v bW0 = *(const s8v*)(wrowB + (C) * KC);                              \
        s8v bW1 = *(const s8v*)(wrowB + (C) * KC + 32);                         \
        if (PF) load_um(um, uR, mR, (C) + 1);                                   \
        const unsigned char* mbase = smem + bsel * 32768;                       \
        _Pragma("unroll")                                                       \
        for (int nt = 0; nt < 16; ++nt) {                                       \
            s8v bM0 = *(const s8v*)(mbase + nt * 2048 + off0);                  \
            s8v bM1 = *(const s8v*)(mbase + nt * 2048 + off1);                  \
            accL[nt] = __builtin_amdgcn_mfma_f32_16x16x32_bf16(FC.s0, bM0, accL[nt], 0, 0, 0); \
            accD[nt] = __builtin_amdgcn_mfma_f32_16x16x32_bf16(FC.d0, bM0, accD[nt], 0, 0, 0); \
            accL[nt] = __builtin_amdgcn_mfma_f32_16x16x32_bf16(FC.s1, bM1, accL[nt], 0, 0, 0); \
            accD[nt] = __builtin_amdgcn_mfma_f32_16x16x32_bf16(FC.d1, bM1, accD[nt], 0, 0, 0); \
        }                                                                       \
        accH = __builtin_amdgcn_mfma_f32_16x16x32_bf16(FC.s0, bW0, accH, 0, 0, 0); \
        accH = __builtin_amdgcn_mfma_f32_16x16x32_bf16(FC.s1, bW1, accH, 0, 0, 0); \
        if (PF) cvt_frag(um, FN, sd2);                                          \
        __builtin_amdgcn_sched_barrier(0);                                      \
        asm volatile("s_waitcnt vmcnt(0)" ::: "memory");                        \
        __builtin_amdgcn_s_barrier();                                           \
        __builtin_amdgcn_sched_barrier(0);                                      \
    }

    for (int cc = 0; cc < NCHUNK; cc += 2) {
        CHUNK_BODY(cc,     fA, fB, (cc     < NCHUNK - 1));
        CHUNK_BODY(cc + 1, fB, fA, (cc + 1 < NCHUNK - 1));
    }
#undef CHUNK_BODY

    // ---- classification head (cols 0,1 live in lanes la=0,1) ----
    if (la < 2) {
#pragma unroll
        for (int j = 0; j < 4; ++j) {
            int gr = row0 + w * 16 + lb * 4 + j;
            out[1 + gr * 2 + la] = accH[j] + bout[la];
        }
    }
    // ---- ||d||^2 per row: reduce over the 4 lb col-groups ----
    sd2 += __shfl_xor(sd2, 16);
    sd2 += __shfl_xor(sd2, 32);   // every lane now holds row (l&15)'s total

    // ---- softmax over n (C layout: col=la, row=lb*4+j) ----
    float mr0, mr1, mr2, mr3;
    {
        ff4 mx = accL[0];
#pragma unroll
        for (int nt = 1; nt < 16; ++nt) {
            mx[0] = fmaxf(mx[0], accL[nt][0]); mx[1] = fmaxf(mx[1], accL[nt][1]);
            mx[2] = fmaxf(mx[2], accL[nt][2]); mx[3] = fmaxf(mx[3], accL[nt][3]);
        }
#pragma unroll
        for (int s = 1; s < 16; s <<= 1) {
            mx[0] = fmaxf(mx[0], __shfl_xor(mx[0], s));
            mx[1] = fmaxf(mx[1], __shfl_xor(mx[1], s));
            mx[2] = fmaxf(mx[2], __shfl_xor(mx[2], s));
            mx[3] = fmaxf(mx[3], __shfl_xor(mx[3], s));
        }
        mr0 = mx[0]; mr1 = mx[1]; mr2 = mx[2]; mr3 = mx[3];
    }
    ff4 sumv = (ff4)0.0f;
#pragma unroll
    for (int nt = 0; nt < 16; ++nt) {
        accL[nt][0] = __expf(accL[nt][0] - mr0);
        accL[nt][1] = __expf(accL[nt][1] - mr1);
        accL[nt][2] = __expf(accL[nt][2] - mr2);
        accL[nt][3] = __expf(accL[nt][3] - mr3);
        sumv[0] += accL[nt][0]; sumv[1] += accL[nt][1];
        sumv[2] += accL[nt][2]; sumv[3] += accL[nt][3];
    }
#pragma unroll
    for (int s = 1; s < 16; s <<= 1) {
        sumv[0] += __shfl_xor(sumv[0], s); sumv[1] += __shfl_xor(sumv[1], s);
        sumv[2] += __shfl_xor(sumv[2], s); sumv[3] += __shfl_xor(sumv[3], s);
    }
    const float i0v = 1.0f / sumv[0], i1v = 1.0f / sumv[1];
    const float i2v = 1.0f / sumv[2], i3v = 1.0f / sumv[3];
    ff4 cross = (ff4)0.0f;
#pragma unroll
    for (int nt = 0; nt < 16; ++nt) {
        accL[nt][0] *= i0v; accL[nt][1] *= i1v; accL[nt][2] *= i2v; accL[nt][3] *= i3v;
        cross[0] = fmaf(accL[nt][0], accD[nt][0], cross[0]);
        cross[1] = fmaf(accL[nt][1], accD[nt][1], cross[1]);
        cross[2] = fmaf(accL[nt][2], accD[nt][2], cross[2]);
        cross[3] = fmaf(accL[nt][3], accD[nt][3], cross[3]);
    }
#pragma unroll
    for (int s = 1; s < 16; s <<= 1) {
        cross[0] += __shfl_xor(cross[0], s); cross[1] += __shfl_xor(cross[1], s);
        cross[2] += __shfl_xor(cross[2], s); cross[3] += __shfl_xor(cross[3], s);
    }

    // ---- stage attn (bf16) to this wave's LDS tile (aliases sM, post-barrier) ----
    unsigned short* myAttn = sAttn + w * (16 * APAD);
    {
        const int rb = lb << 2;
#pragma unroll
        for (int nt = 0; nt < 16; ++nt) {
            const int cc2 = nt * 16 + la;
            myAttn[(rb + 0) * APAD + cc2] = (unsigned short)bf16r(accL[nt][0]);
            myAttn[(rb + 1) * APAD + cc2] = (unsigned short)bf16r(accL[nt][1]);
            myAttn[(rb + 2) * APAD + cc2] = (unsigned short)bf16r(accL[nt][2]);
            myAttn[(rb + 3) * APAD + cc2] = (unsigned short)bf16r(accL[nt][3]);
        }
    }
    // same-wave LDS write->read: compiler handles lgkmcnt ordering

    // ---- gv = attn @ G (G symmetric -> row-major fragments valid as B) ----
    ff4 accG[16];
#pragma unroll
    for (int i = 0; i < 16; ++i) accG[i] = (ff4)0.0f;
#pragma unroll
    for (int ks = 0; ks < 8; ++ks) {
        const int ko = ks * 32 + (lb << 3);
        s8v aA = *(const s8v*)(myAttn + la * APAD + ko);
#pragma unroll
        for (int nt = 0; nt < 16; ++nt) {
            s8v bG = *(const s8v*)(Gbf + (size_t)(nt * 16 + la) * Nn + ko);
            accG[nt] = __builtin_amdgcn_mfma_f32_16x16x32_bf16(aA, bG, accG[nt], 0, 0, 0);
        }
    }
    ff4 quad = (ff4)0.0f;
#pragma unroll
    for (int nt = 0; nt < 16; ++nt) {
        quad[0] = fmaf(accL[nt][0], accG[nt][0], quad[0]);
        quad[1] = fmaf(accL[nt][1], accG[nt][1], quad[1]);
        quad[2] = fmaf(accL[nt][2], accG[nt][2], quad[2]);
        quad[3] = fmaf(accL[nt][3], accG[nt][3], quad[3]);
    }
#pragma unroll
    for (int s = 1; s < 16; s <<= 1) {
        quad[0] += __shfl_xor(quad[0], s); quad[1] += __shfl_xor(quad[1], s);
        quad[2] += __shfl_xor(quad[2], s); quad[3] += __shfl_xor(quad[3], s);
    }

    // ---- score & per-wave loss partial ----
    float sdr = __shfl(sd2, (lb << 2) + la);   // row r = lb*4+la lives in lane r
    float val = 0.f;
    if (la < 4) {
        const int r = (lb << 2) + la;
        float cr = (la == 0) ? cross[0] : (la == 1) ? cross[1] : (la == 2) ? cross[2] : cross[3];
        float qd = (la == 0) ? quad[0]  : (la == 1) ? quad[1]  : (la == 2) ? quad[2]  : quad[3];
        float s2 = sdr + 2.0f * cr + qd;
        float sc = sqrtf(fmaxf(s2, 0.0f));
        const int gr = row0 + w * 16 + r;
        val = (float)(2 * label[gr] - 1) * sc;
    }
#pragma unroll
    for (int s = 1; s < 64; s <<= 1) val += __shfl_xor(val, s);
    if (l == 0) partials[blockIdx.x * 4 + w] = val;
}

// ---- deterministic final reduction of per-wave partials -> loss ----
__global__ void finalize_kernel(const float* __restrict__ partials, float* __restrict__ out,
                                int np, float invB) {
    const int t = threadIdx.x;
    float v = 0.f;
    for (int i = t; i < np; i += 256) v += partials[i];
#pragma unroll
    for (int s = 1; s < 64; s <<= 1) v += __shfl_xor(v, s);
    __shared__ float ws4[4];
    if ((t & 63) == 0) ws4[t >> 6] = v;
    __syncthreads();
    if (t == 0) out[0] = (ws4[0] + ws4[1] + ws4[2] + ws4[3]) * invB;
}

extern "C" void kernel_launch(void* const* d_in, const int* in_sizes, int n_in,
                              void* d_out, int out_size, void* d_ws, size_t ws_size,
                              hipStream_t stream) {
    const float* user  = (const float*)d_in[0];
    const float* music = (const float*)d_in[1];
    const float* mem   = (const float*)d_in[2];
    const float* Wout  = (const float*)d_in[3];
    const float* bout  = (const float*)d_in[4];
    const int*   label = (const int*)d_in[5];
    const int Bn   = in_sizes[0] / Hd;   // 65536
    const int nblk = Bn / 64;            // 1024

    unsigned short* memB = (unsigned short*)d_ws;                                  // 512 KB
    unsigned short* Wbf  = (unsigned short*)((char*)d_ws + 524288);                // 4 KB
    unsigned short* Gbf  = (unsigned short*)((char*)d_ws + 524288 + 4096);         // 128 KB
    float* partials      = (float*)((char*)d_ws + 524288 + 4096 + 131072);         // 16 KB

    conv_mem_kernel<<<128, 256, 0, stream>>>(mem, memB);
    conv_w_kernel<<<1, 256, 0, stream>>>(Wout, Wbf);
    gram_kernel<<<64, 256, 0, stream>>>(mem, Gbf);
    fused_kernel<<<nblk, 256, 0, stream>>>(user, music, bout, label, memB, Wbf, Gbf,
                                           (float*)d_out, partials);
    finalize_kernel<<<1, 256, 0, stream>>>(partials, (float*)d_out, nblk * 4, 1.0f / (float)Bn);
}